// Round 9
// baseline (466.460 us; speedup 1.0000x reference)
//
#include <hip/hip_runtime.h>
#include <hip/hip_bf16.h>
#include <stdint.h>

// ---- types ----
typedef float   floatx4  __attribute__((ext_vector_type(4)));
typedef float   floatx16 __attribute__((ext_vector_type(16)));
typedef int     intx4    __attribute__((ext_vector_type(4)));
typedef int     intx8    __attribute__((ext_vector_type(8)));
typedef _Float16 halfx8  __attribute__((ext_vector_type(8)));
typedef _Float16 halfx4  __attribute__((ext_vector_type(4)));
typedef _Float16 half2v  __attribute__((ext_vector_type(2)));

#define NROW 8192
#define NDIM 2048        // elements = bytes (fp8)
#define BM 128
#define SLICE 64         // bytes per row per K-slice = K=64 fp8 (one 32x32x64 MFMA)
#define NSLICE 32        // NDIM / SLICE
#define NSTRIP 64                       // NROW/BM
#define NTILE (NSTRIP*(NSTRIP+1)/2)     // 2080 total tiles (= 8*260 exactly)
#define NPOSB 256        // pos blocks prepended to the fused grid
#define DT_LD 136        // Dt row stride in halves (272 B; rows 16B-aligned)
#define KL_SYM 64        // one 5-list per row per other-strip
#define SLOT_P 8         // halves per list slot: 5 values + 3 sentinel pads (16B)
#define MERGE_BLOCKS 256 // k_merge_sym grid
#define BOOST_INV 0.6944444444f   // 1/1.44
// xbt: fragment-permuted A copy.  [strip(64)][slice(32)][g(4)][lane(64)] x 32B.
// entry(strip,s,g,l) = xb[strip*128 + 32*g + (l&31)][64*s + 32*(l>>5) .. +32]
// -> A-frag load for wave wm, group g=2wm+ti is ONE contiguous 2KB span.
#define XBT_STRIP 262144   // 32*8192
#define XBT_SLICE 8192

// insert v into descending-sorted a[5] (keeps 5 largest)  [f32 scalar]
__device__ __forceinline__ void ins_desc(float (&a)[5], float v) {
#pragma unroll
    for (int k = 0; k < 5; ++k) { float hi = fmaxf(a[k], v); float lo = fminf(a[k], v); a[k] = hi; v = lo; }
}
// insert v into ascending-sorted a[5] (keeps 5 smallest)  [f32 scalar]
__device__ __forceinline__ void ins_asc(float (&a)[5], float v) {
#pragma unroll
    for (int k = 0; k < 5; ++k) { float lo = fminf(a[k], v); float hi = fmaxf(a[k], v); a[k] = lo; v = hi; }
}

__device__ __forceinline__ int   h2bits(half2v v) { return __builtin_bit_cast(int, v); }
__device__ __forceinline__ half2v bits2h(int v)   { return __builtin_bit_cast(half2v, v); }
// packed insertion: two independent sorted top-5 lists (lo/hi half)
__device__ __forceinline__ void ins_desc2(half2v (&a)[5], half2v v) {
#pragma unroll
    for (int k = 0; k < 5; ++k) {
        half2v hi = __builtin_elementwise_max(a[k], v);
        half2v lo = __builtin_elementwise_min(a[k], v);
        a[k] = hi; v = lo;
    }
}
__device__ __forceinline__ void ins_asc2(half2v (&a)[5], half2v v) {
#pragma unroll
    for (int k = 0; k < 5; ++k) {
        half2v lo = __builtin_elementwise_min(a[k], v);
        half2v hi = __builtin_elementwise_max(a[k], v);
        a[k] = lo; v = hi;
    }
}

__device__ __forceinline__ void load_lds16(const void* g, void* l) {
    // async global->LDS, 16B/lane, dest = wave-uniform base + lane*16
    __builtin_amdgcn_global_load_lds((__attribute__((address_space(1))) void*)(void*)g,
                                     (__attribute__((address_space(3))) void*)l,
                                     16, 0, 0);
}

// ---- kernel 1: L2 normalize rows, write fp8-e4m3 row-major xb + fragment-
// permuted xbt + sq.  One wave per row; xbt stores are 8x32B scatter/instr.
__global__ __launch_bounds__(256) void k_normalize(const float* __restrict__ feats,
                                                   unsigned char* __restrict__ xb,
                                                   unsigned char* __restrict__ xbt,
                                                   float* __restrict__ sq) {
    const int lane = threadIdx.x & 63;
    const int row = (blockIdx.x << 2) + (threadIdx.x >> 6);
    const float* f = feats + (size_t)row * NDIM;
    float4 v[8];
    float ss = 0.f;
#pragma unroll
    for (int i = 0; i < 8; ++i) {
        v[i] = *(const float4*)(f + ((i << 6) + lane) * 4);
        ss += v[i].x * v[i].x + v[i].y * v[i].y + v[i].z * v[i].z + v[i].w * v[i].w;
    }
#pragma unroll
    for (int o = 32; o > 0; o >>= 1) ss += __shfl_xor(ss, o);
    float inv = 1.0f / fmaxf(sqrtf(ss), 1e-12f);
    if (lane == 0) sq[row] = ss * inv * inv;
    unsigned char* xo = xb + (size_t)row * NDIM;
    // xbt dest pieces constant per (row, lane-derived):
    const int strip = row >> 7, rr = row & 127, g = rr >> 5, m32r = rr & 31;
    unsigned char* bt = xbt + (size_t)strip * XBT_STRIP + g * 2048 + m32r * 32
                      + ((lane >> 4) * XBT_SLICE) + (((lane >> 3) & 1) * 1024) + 4 * (lane & 7);
#pragma unroll
    for (int i = 0; i < 8; ++i) {
        int w0 = __builtin_amdgcn_cvt_pk_fp8_f32(v[i].x * inv, v[i].y * inv, 0, false);
        w0     = __builtin_amdgcn_cvt_pk_fp8_f32(v[i].z * inv, v[i].w * inv, w0, true);
        *(int*)(xo + ((i << 6) + lane) * 4) = w0;
        *(int*)(bt + (size_t)4 * i * XBT_SLICE) = w0;   // sG = 4i + (lane>>4)
    }
}

// ---- scan: Dt holds PRE-CLASSIFIED nv (boosted d2; +inf for same-label/diag).
// Insertion-only: load b128 + 4x ins_asc2.
__device__ __forceinline__ void scan_half_row_neg(const _Float16* Dt_,
        int srow, int shalf, float (&neg5)[5]) {
    const int s2 = 2 * (srow & 7);
    const int PINF2 = 0x7C007C00;
    half2v n5[5];
#pragma unroll
    for (int k = 0; k < 5; ++k) n5[k] = bits2h(PINF2);
#pragma unroll
    for (int c8 = 0; c8 < 8; ++c8) {
        const int pc = ((shalf * 8 + c8) + s2) & 15;      // physical 16B chunk
        intx4 v = *(const intx4*)(Dt_ + srow * DT_LD + pc * 8);
#pragma unroll
        for (int e = 0; e < 4; ++e) ins_asc2(n5, bits2h(v[e]));
    }
    // fold hi-halves into lo halves (top5 ⊆ union of half-top5s)
    half2v tn[5];
#pragma unroll
    for (int k = 0; k < 5; ++k)
        tn[k] = bits2h((int)__builtin_amdgcn_alignbit((unsigned)h2bits(n5[k]), (unsigned)h2bits(n5[k]), 16));
#pragma unroll
    for (int k = 0; k < 5; ++k) ins_asc2(n5, tn[k]);
#pragma unroll
    for (int k = 0; k < 5; ++k) neg5[k] = (float)n5[k][0];
}

// merge the two half-row lists (adjacent lanes) and emit one coalesced b128
__device__ __forceinline__ void emit_neg(float (&neg5)[5], int shalf,
        _Float16* negp, int gi, int slot) {
    float tn[5];
#pragma unroll
    for (int k = 0; k < 5; ++k) tn[k] = __shfl_xor(neg5[k], 1);
#pragma unroll
    for (int k = 0; k < 5; ++k) { if (tn[k] < neg5[4]) ins_asc(neg5, tn[k]); }
    if (shalf == 0) {
        const float PINF = __builtin_inff();
        halfx8 hn;
#pragma unroll
        for (int k = 0; k < 5; ++k) hn[k] = (_Float16)neg5[k];
        hn[5] = hn[6] = hn[7] = (_Float16)PINF;
        *(halfx8*)(negp + ((size_t)slot * NROW + gi) * SLOT_P) = hn;
    }
}

// ---- fused kernel 2: blocks [0,256) = positives; [256, 2336) = tiles.
// R20 = R19 byte-identical EXCEPT __launch_bounds__(256,4): R19's A/B showed
// two different K-loops (all-LDS 109.5 / A-direct 106.2) land at the same
// latency-bound plateau with Occupancy ~27% (2.15 blocks/CU).  The 36.8KB LDS
// geometry fits 4 blocks/CU (4x36864 = 147456 <= 163840) and VGPR=72 < 128 cap
// at 4 waves/EU; only the (256,3) bound held residency at 3.  One variable.
__global__ __launch_bounds__(256, 4) void k_main(
        const unsigned char* __restrict__ xb, const unsigned char* __restrict__ xbt,
        const float* __restrict__ sq,
        const int* __restrict__ labels, const int* __restrict__ camids,
        _Float16* __restrict__ negp, _Float16* __restrict__ posf) {
    __shared__ __align__(16) char smem[36864];

    const int tid = threadIdx.x;
    const int w = tid >> 6, lane = tid & 63;
    const int m32 = lane & 31;
    const int hi = lane >> 5;
    const int key = (lane >> 1) & 3;
    const int p0 = ((2 * hi + key) & 3) * 16;
    const int p1 = ((2 * hi + 1 + key) & 3) * 16;
    const float FINF = __builtin_inff();
    const float NINF = -FINF;

    if (blockIdx.x < NPOSB) {
        // ================= positives path (one block per label) =================
        char* stg0 = smem;                                   // 3 x 4096
        _Float16* D2 = (_Float16*)(smem + 12288);            // [64][72] halves
        int* mem = (int*)(smem + 21504);                     // 64 ints
        unsigned short* mlc = (unsigned short*)(smem + 21760);
        float* msq = (float*)(smem + 21888);
        int* cntp = (int*)(smem + 22144);

        const int L = blockIdx.x;
        if (tid == 0) *cntp = 0;
        __syncthreads();
        for (int i = tid; i < NROW; i += 256) {
            if (labels[i] == L) {
                int slot = atomicAdd(cntp, 1);
                if (slot < 64) mem[slot] = i;
            }
        }
        __syncthreads();
        const int cnt = min(*cntp, 64);   // P(group>64) ~ 2e-6
        if (tid < 64) {
            if (tid < cnt) {
                int gi = mem[tid];
                mlc[tid] = (unsigned short)((labels[gi] << 4) | camids[gi]);
                msq[tid] = sq[gi];
            } else {
                mem[tid] = 0; mlc[tid] = 0xFFFF; msq[tid] = 0.f;  // sentinel
            }
        }
        __syncthreads();

        const int wm = w >> 1, wn = w & 1;
        const int lr = lane >> 2;
        const int lcb = (((lane & 3) - ((lane >> 3) & 3)) & 3) * 16;
        const int myrow = mem[w * 16 + lr];          // wave w stages rows w*16..+15

        auto pstage = [&](int buf, int koff) {
            load_lds16(xb + (size_t)myrow * NDIM + koff + lcb,
                       stg0 + (buf << 12) + w * 1024);
        };

        floatx16 acc;
#pragma unroll
        for (int r = 0; r < 16; ++r) acc[r] = 0.f;

        pstage(0, 0);                    // depth-2 fill (1 load/wave/slice)
        pstage(1, SLICE);
        for (int s = 0; s < NSLICE; ++s) {
            if (s + 2 < NSLICE) pstage((s + 2) % 3, (s + 2) * SLICE);
            if (s < NSLICE - 2)       asm volatile("s_waitcnt vmcnt(2)" ::: "memory");
            else if (s == NSLICE - 2) asm volatile("s_waitcnt vmcnt(1)" ::: "memory");
            else                      asm volatile("s_waitcnt vmcnt(0)" ::: "memory");
            __builtin_amdgcn_s_barrier();
            asm volatile("" ::: "memory");
            const char* Ab = stg0 + ((s % 3) << 12);
            const char* ap = Ab + (wm * 32 + m32) * SLICE;
            intx4 alo = *(const intx4*)(ap + p0);
            intx4 ahi = *(const intx4*)(ap + p1);
            intx8 af = __builtin_shufflevector(alo, ahi, 0, 1, 2, 3, 4, 5, 6, 7);
            const char* bp = Ab + (wn * 32 + m32) * SLICE;
            intx4 blo = *(const intx4*)(bp + p0);
            intx4 bhi = *(const intx4*)(bp + p1);
            intx8 bf = __builtin_shufflevector(blo, bhi, 0, 1, 2, 3, 4, 5, 6, 7);
            acc = __builtin_amdgcn_mfma_scale_f32_32x32x64_f8f6f4(af, bf, acc, 0, 0, 0, 127, 0, 127);
            asm volatile("" ::: "memory");
            __builtin_amdgcn_s_barrier();
            asm volatile("" ::: "memory");
        }

        // epilogue: masked d2 -> D2[il][jl]; valid pos <=> same label, cross-cam
        {
            const int jl = (w & 1) * 32 + m32;
            const int lcj = (int)mlc[jl];
            const float sj = msq[jl];
            const int wm2 = w >> 1;
#pragma unroll
            for (int r = 0; r < 16; ++r) {
                const int il = wm2 * 32 + (r & 3) + 8 * (r >> 2) + 4 * hi;
                float d2 = fmaxf(msq[il] + sj - 2.0f * acc[r], 1e-12f);
                const int x = (int)mlc[il] ^ lcj;
                bool posv = ((x & 0xFFF0) == 0) & ((x & 15) != 0);
                D2[il * 72 + jl] = posv ? (_Float16)d2 : (_Float16)NINF;
            }
        }
        __syncthreads();

        // per-row top5: 4 threads/row x 16 cols, packed insert + shfl merge
        {
            const int prow = tid >> 2, q = tid & 3;
            const int NINF2 = 0xFC00FC00;
            half2v p5h[5];
#pragma unroll
            for (int k = 0; k < 5; ++k) p5h[k] = bits2h(NINF2);
            const _Float16* dp = D2 + prow * 72 + q * 16;
            intx4 v0 = *(const intx4*)dp;
            intx4 v1 = *(const intx4*)(dp + 8);
#pragma unroll
            for (int e = 0; e < 4; ++e) ins_desc2(p5h, bits2h(v0[e]));
#pragma unroll
            for (int e = 0; e < 4; ++e) ins_desc2(p5h, bits2h(v1[e]));
            half2v tp[5];
#pragma unroll
            for (int k = 0; k < 5; ++k)
                tp[k] = bits2h((int)__builtin_amdgcn_alignbit((unsigned)h2bits(p5h[k]), (unsigned)h2bits(p5h[k]), 16));
#pragma unroll
            for (int k = 0; k < 5; ++k) ins_desc2(p5h, tp[k]);
            float p5[5];
#pragma unroll
            for (int k = 0; k < 5; ++k) p5[k] = (float)p5h[k][0];
#pragma unroll
            for (int o = 1; o <= 2; o <<= 1) {
                float tq[5];
#pragma unroll
                for (int k = 0; k < 5; ++k) tq[k] = __shfl_xor(p5[k], o);
#pragma unroll
                for (int k = 0; k < 5; ++k) { if (tq[k] > p5[4]) ins_desc(p5, tq[k]); }
            }
            if (q == 0 && prow < cnt) {
                halfx8 hp;
#pragma unroll
                for (int k = 0; k < 5; ++k) hp[k] = (_Float16)p5[k];
                hp[5] = hp[6] = hp[7] = (_Float16)NINF;
                *(halfx8*)(posf + (size_t)mem[prow] * SLOT_P) = hp;
            }
        }
        return;
    }

    // ================= tile (negatives) path =================
    _Float16* Dt = (_Float16*)smem;           // [0, 34816) aliases B staging
    float* sqr_s = (float*)(smem + 34816);
    float* sqc_s = sqr_s + BM;
    unsigned short* labcam_a = (unsigned short*)(sqc_s + BM);
    unsigned short* labcam_b = labcam_a + BM;

    const int wm = w >> 1, wn = w & 1;

    // supertile decode; XCD-chunked (2080 = 8*260 exact, bijective)
    int a, b;
    {
        int bx = blockIdx.x - NPOSB;
        int o = (bx & 7) * (NTILE / 8) + (bx >> 3);
        if (o < 1792) {                          // 28 off-diag supertiles x 64
            int st = o >> 6;                     // SA>SB triangle, 8 strips
            int SA = (int)((1.0f + sqrtf(8.0f * (float)st + 1.0f)) * 0.5f);
            while (SA * (SA - 1) / 2 > st) --SA;
            while (SA * (SA + 1) / 2 <= st) ++SA;
            int SB = st - SA * (SA - 1) / 2;
            int inner = o & 63;
            a = SA * 8 + (inner >> 3);
            b = SB * 8 + (inner & 7);
        } else {                                 // 8 diag supertiles x 36
            int idx = o - 1792;
            int st = idx / 36;
            int inner = idx - st * 36;           // triangle incl diagonal
            int ia = (int)((sqrtf(8.0f * (float)inner + 1.0f) - 1.0f) * 0.5f);
            while (ia * (ia + 1) / 2 > inner) --ia;
            while ((ia + 1) * (ia + 2) / 2 <= inner) ++ia;
            int ib = inner - ia * (ia + 1) / 2;
            a = st * 8 + ia;
            b = st * 8 + ib;
        }
    }
    const int r0 = a * BM, c0 = b * BM;

    // side arrays first (their auto-inserted waits precede all staging issues)
    if (tid < BM) {
        int gi = r0 + tid;
        sqr_s[tid] = sq[gi];
        labcam_a[tid] = (unsigned short)((labels[gi] << 4) | camids[gi]);
    } else {
        int t2 = tid - BM;
        int gj = c0 + t2;
        sqc_s[t2] = sq[gj];
        labcam_b[t2] = (unsigned short)((labels[gj] << 4) | camids[gj]);
    }

    // B staging: 64 lanes x 16B = 16 rows x 64B per issue, additive chunk rotate
    const int lr = lane >> 2;
    const int lc = (((lane & 3) - ((lane >> 3) & 3)) & 3) * 16;
    auto stageB = [&](int buf, int koff) {
        char* Bsb = smem + (buf << 13);          // 4 x 8KB ring
#pragma unroll
        for (int q = 0; q < 2; ++q) {
            const int ra = w * 32 + q * 16;
            load_lds16(xb + (size_t)(c0 + ra + lr) * NDIM + koff + lc, Bsb + ra * SLICE);
        }
    };

    // A operand: coalesced direct loads from xbt (lane-contiguous 32B)
    const unsigned char* aptrA = xbt + (size_t)a * XBT_STRIP + (2 * wm) * 2048 + lane * 32;
    const unsigned char* aptrB = aptrA + 2048;   // g = 2*wm + 1

    intx4 xa0, xa1, xa2, xa3;      // A-frag set for even slices (ti0, ti1)
    intx4 ya0, ya1, ya2, ya3;      // A-frag set for odd slices

    // prologue: depth-2 for both streams (FIFO: B0,A0,B1,A1 = 12 ops)
    stageB(0, 0);
    xa0 = *(const intx4*)(aptrA);       xa1 = *(const intx4*)(aptrA + 16);
    xa2 = *(const intx4*)(aptrB);       xa3 = *(const intx4*)(aptrB + 16);
    stageB(1, SLICE);
    ya0 = *(const intx4*)(aptrA + XBT_SLICE);      ya1 = *(const intx4*)(aptrA + XBT_SLICE + 16);
    ya2 = *(const intx4*)(aptrB + XBT_SLICE);      ya3 = *(const intx4*)(aptrB + XBT_SLICE + 16);

    const int srow = tid >> 1;       // scan: 2 threads per row
    const int shalf = tid & 1;

    floatx16 acc[2][2];
#pragma unroll
    for (int ti = 0; ti < 2; ++ti)
#pragma unroll
        for (int tj = 0; tj < 2; ++tj)
#pragma unroll
            for (int r = 0; r < 16; ++r) acc[ti][tj][r] = 0.f;

    for (int s = 0; s < NSLICE; s += 2) {
        // ---- slice s (even): A in xa*, B in buf s&3 ----
        if (s + 2 < NSLICE) {
            stageB((s + 2) & 3, (s + 2) * SLICE);
            asm volatile("s_waitcnt vmcnt(8)" ::: "memory");
        } else {
            asm volatile("s_waitcnt vmcnt(6)" ::: "memory");
        }
        __builtin_amdgcn_s_barrier();
        asm volatile("" ::: "memory");
        {
            const char* Bb = smem + ((s & 3) << 13);
            intx8 bf0, bf1;
            {
                const char* bp = Bb + (wn * 64 + m32) * SLICE;
                intx4 lo = *(const intx4*)(bp + p0);
                intx4 h4 = *(const intx4*)(bp + p1);
                bf0 = __builtin_shufflevector(lo, h4, 0, 1, 2, 3, 4, 5, 6, 7);
            }
            {
                const char* bp = Bb + (wn * 64 + 32 + m32) * SLICE;
                intx4 lo = *(const intx4*)(bp + p0);
                intx4 h4 = *(const intx4*)(bp + p1);
                bf1 = __builtin_shufflevector(lo, h4, 0, 1, 2, 3, 4, 5, 6, 7);
            }
            __builtin_amdgcn_s_setprio(1);
            intx8 af0 = __builtin_shufflevector(xa0, xa1, 0, 1, 2, 3, 4, 5, 6, 7);
            intx8 af1 = __builtin_shufflevector(xa2, xa3, 0, 1, 2, 3, 4, 5, 6, 7);
            acc[0][0] = __builtin_amdgcn_mfma_scale_f32_32x32x64_f8f6f4(af0, bf0, acc[0][0], 0, 0, 0, 127, 0, 127);
            acc[0][1] = __builtin_amdgcn_mfma_scale_f32_32x32x64_f8f6f4(af0, bf1, acc[0][1], 0, 0, 0, 127, 0, 127);
            acc[1][0] = __builtin_amdgcn_mfma_scale_f32_32x32x64_f8f6f4(af1, bf0, acc[1][0], 0, 0, 0, 127, 0, 127);
            acc[1][1] = __builtin_amdgcn_mfma_scale_f32_32x32x64_f8f6f4(af1, bf1, acc[1][1], 0, 0, 0, 127, 0, 127);
            __builtin_amdgcn_s_setprio(0);
        }
        if (s + 2 < NSLICE) {
            const size_t ko = (size_t)(s + 2) * XBT_SLICE;
            xa0 = *(const intx4*)(aptrA + ko); xa1 = *(const intx4*)(aptrA + ko + 16);
            xa2 = *(const intx4*)(aptrB + ko); xa3 = *(const intx4*)(aptrB + ko + 16);
        }
        // ---- slice s+1 (odd): A in ya*, B in buf (s+1)&3 ----
        if (s + 3 < NSLICE) {
            stageB((s + 3) & 3, (s + 3) * SLICE);
            asm volatile("s_waitcnt vmcnt(8)" ::: "memory");
        } else {
            asm volatile("s_waitcnt vmcnt(0)" ::: "memory");
        }
        __builtin_amdgcn_s_barrier();
        asm volatile("" ::: "memory");
        {
            const char* Bb = smem + (((s + 1) & 3) << 13);
            intx8 bf0, bf1;
            {
                const char* bp = Bb + (wn * 64 + m32) * SLICE;
                intx4 lo = *(const intx4*)(bp + p0);
                intx4 h4 = *(const intx4*)(bp + p1);
                bf0 = __builtin_shufflevector(lo, h4, 0, 1, 2, 3, 4, 5, 6, 7);
            }
            {
                const char* bp = Bb + (wn * 64 + 32 + m32) * SLICE;
                intx4 lo = *(const intx4*)(bp + p0);
                intx4 h4 = *(const intx4*)(bp + p1);
                bf1 = __builtin_shufflevector(lo, h4, 0, 1, 2, 3, 4, 5, 6, 7);
            }
            __builtin_amdgcn_s_setprio(1);
            intx8 af0 = __builtin_shufflevector(ya0, ya1, 0, 1, 2, 3, 4, 5, 6, 7);
            intx8 af1 = __builtin_shufflevector(ya2, ya3, 0, 1, 2, 3, 4, 5, 6, 7);
            acc[0][0] = __builtin_amdgcn_mfma_scale_f32_32x32x64_f8f6f4(af0, bf0, acc[0][0], 0, 0, 0, 127, 0, 127);
            acc[0][1] = __builtin_amdgcn_mfma_scale_f32_32x32x64_f8f6f4(af0, bf1, acc[0][1], 0, 0, 0, 127, 0, 127);
            acc[1][0] = __builtin_amdgcn_mfma_scale_f32_32x32x64_f8f6f4(af1, bf0, acc[1][0], 0, 0, 0, 127, 0, 127);
            acc[1][1] = __builtin_amdgcn_mfma_scale_f32_32x32x64_f8f6f4(af1, bf1, acc[1][1], 0, 0, 0, 127, 0, 127);
            __builtin_amdgcn_s_setprio(0);
        }
        if (s + 3 < NSLICE) {
            const size_t ko = (size_t)(s + 3) * XBT_SLICE;
            ya0 = *(const intx4*)(aptrA + ko); ya1 = *(const intx4*)(aptrA + ko + 16);
            ya2 = *(const intx4*)(aptrB + ko); ya3 = *(const intx4*)(aptrB + ko + 16);
        }
    }
    __syncthreads();                 // all waves' last ds_reads done; Dt safe

    // ---- pass 1: classify once (symmetric), write nv row-major; acc := nv ----
    // 32x32 C layout: col = lane&31, row = (reg&3)+8*(reg>>2)+4*hi
    {
        const int jl0 = wn * 64 + m32, jl1 = jl0 + 32;
        const float sj0 = sqc_s[jl0], sj1 = sqc_s[jl1];
        const int lb0 = (int)labcam_b[jl0], lb1 = (int)labcam_b[jl1];
        const int jc0 = jl0 >> 3, j7_0 = jl0 & 7;
        const int jc1 = jl1 >> 3, j7_1 = jl1 & 7;
#pragma unroll
        for (int ti = 0; ti < 2; ++ti) {
#pragma unroll
            for (int r = 0; r < 16; ++r) {
                const int il = wm * 64 + ti * 32 + (r & 3) + 8 * (r >> 2) + 4 * hi;
                const float si = sqr_s[il];
                const int la = (int)labcam_a[il];
                const int rot = 2 * (il & 7);
                _Float16* drow = Dt + il * DT_LD;

                float d2 = fmaxf(si + sj0 - 2.0f * acc[ti][0][r], 1e-12f);
                int x = la ^ lb0;
                float nv = (x & 15) ? d2 : d2 * BOOST_INV;
                nv = (x & 0xFFF0) ? nv : FINF;
                acc[ti][0][r] = nv;
                drow[(((jc0 + rot) & 15) << 3) + j7_0] = (_Float16)nv;

                d2 = fmaxf(si + sj1 - 2.0f * acc[ti][1][r], 1e-12f);
                x = la ^ lb1;
                nv = (x & 15) ? d2 : d2 * BOOST_INV;
                nv = (x & 0xFFF0) ? nv : FINF;
                acc[ti][1][r] = nv;
                drow[(((jc1 + rot) & 15) << 3) + j7_1] = (_Float16)nv;
            }
        }
    }
    __syncthreads();

    float neg5[5];
    scan_half_row_neg(Dt, srow, shalf, neg5);
    emit_neg(neg5, shalf, negp, r0 + srow, b);

    if (a != b) {
        __syncthreads();             // pass-1 scan reads done before Dt overwrite
        // ---- pass 2: re-layout nv transposed from acc (no recompute) ----
#pragma unroll
        for (int tj = 0; tj < 2; ++tj) {
#pragma unroll
            for (int ti = 0; ti < 2; ++ti) {
                const int jl = wn * 64 + tj * 32 + m32;   // Dt row
                const int cw2 = 2 * (jl & 7);
#pragma unroll
                for (int rq = 0; rq < 4; ++rq) {
                    const int base_row = wm * 64 + ti * 32 + 8 * rq + 4 * hi;
                    halfx4 h;
#pragma unroll
                    for (int e = 0; e < 4; ++e) h[e] = (_Float16)acc[ti][tj][rq * 4 + e];
                    const int pch = (((base_row >> 3) + cw2) & 15);
                    *(halfx4*)(Dt + jl * DT_LD + (pch << 3) + 4 * hi) = h;
                }
            }
        }
        __syncthreads();
        scan_half_row_neg(Dt, srow, shalf, neg5);
        emit_neg(neg5, shalf, negp, c0 + srow, a);
    }
}

// ---- kernel 3: merge 64 fp16 neg-lists/row + final pos list ----
__global__ __launch_bounds__(256) void k_merge_sym(const _Float16* __restrict__ negp,
        const _Float16* __restrict__ posf, const int* __restrict__ epoch_p,
        float* __restrict__ out, float* __restrict__ wsum_p, float* __restrict__ wpsum_p) {
    const int t = threadIdx.x;
    const int rl = t & 31;
    const int sg = t >> 5;
    const int row = blockIdx.x * 32 + rl;
    const float NINF = -__builtin_inff(), PINF = __builtin_inff();
    float n5[5] = {PINF, PINF, PINF, PINF, PINF};
    const size_t rbase = (size_t)row * SLOT_P;
#pragma unroll
    for (int s = 0; s < 8; ++s) {
        const size_t off = (size_t)(sg * 8 + s) * ((size_t)NROW * SLOT_P) + rbase;
        halfx8 nv = *(const halfx8*)(negp + off);
#pragma unroll
        for (int e = 0; e < 8; ++e) { float f = (float)nv[e]; if (f < n5[4]) ins_asc(n5, f); }
    }
    __shared__ __align__(16) _Float16 ln[32][8][8];
    const int sw = (sg + rl) & 7;
    {
        halfx8 hn;
#pragma unroll
        for (int k = 0; k < 5; ++k) hn[k] = (_Float16)n5[k];
        hn[5] = hn[6] = hn[7] = (_Float16)PINF;
        *(halfx8*)&ln[rl][sw][0] = hn;
    }
    __syncthreads();
    if (t < 32) {
        float N5[5] = {PINF, PINF, PINF, PINF, PINF};
#pragma unroll
        for (int g = 0; g < 8; ++g) {
            halfx8 nv = *(const halfx8*)&ln[t][g][0];
#pragma unroll
            for (int e = 0; e < 8; ++e) { float f = (float)nv[e]; if (f < N5[4]) ins_asc(N5, f); }
        }
        const int orow = blockIdx.x * 32 + t;
        halfx8 pv = *(const halfx8*)(posf + (size_t)orow * SLOT_P);
        float s = 0.f; int c = 0;
#pragma unroll
        for (int k = 0; k < 5; ++k) { float f = (float)pv[k]; bool fin = (f > NINF); s += fin ? sqrtf(f) : 0.f; c += fin ? 1 : 0; }
        float d_ap = (c > 0) ? s / (float)c : NINF;
        s = 0.f; c = 0;
#pragma unroll
        for (int k = 0; k < 5; ++k) { bool fin = (N5[k] < PINF); s += fin ? sqrtf(N5[k]) : 0.f; c += fin ? 1 : 0; }
        float d_an = (c > 0) ? s / (float)c : PINF;

        out[1 + orow] = d_ap;
        out[1 + NROW + orow] = d_an;
        float diff = d_ap - d_an;
        float w0 = 1.0f / (1.0f + expf(-2.0f * diff));       // sigmoid(ALPHA*diff)
        float p;
        if (*epoch_p < 10) {
            p = fmaxf(diff, 0.0f) + log1pf(expf(-fabsf(diff)));  // stable softplus
        } else {
            p = fmaxf(diff + 0.3f, 0.0f);                    // relu(diff + MARGIN)
        }
        float wp = w0 * p;
#pragma unroll
        for (int o = 16; o > 0; o >>= 1) { w0 += __shfl_down(w0, o, 32); wp += __shfl_down(wp, o, 32); }
        if (t == 0) { wsum_p[blockIdx.x] = w0; wpsum_p[blockIdx.x] = wp; }
    }
}

// ---- kernel 4: finalize loss scalar (256 partials, one wave) ----
__global__ void k_finalize(const float* __restrict__ wsum_p, const float* __restrict__ wpsum_p,
                           float* __restrict__ out) {
    const int t = threadIdx.x;   // 64 threads
    float sw  = wsum_p[t] + wsum_p[t + 64] + wsum_p[t + 128] + wsum_p[t + 192];
    float swp = wpsum_p[t] + wpsum_p[t + 64] + wpsum_p[t + 128] + wpsum_p[t + 192];
#pragma unroll
    for (int o = 32; o > 0; o >>= 1) { sw += __shfl_down(sw, o); swp += __shfl_down(swp, o); }
    if (t == 0) {
        float M = fmaxf(sw / (float)NROW, 1e-12f);
        out[0] = swp / ((float)NROW * M);
    }
}

extern "C" void kernel_launch(void* const* d_in, const int* in_sizes, int n_in,
                              void* d_out, int out_size, void* d_ws, size_t ws_size,
                              hipStream_t stream) {
    const float* feats  = (const float*)d_in[0];
    const int*   labels = (const int*)d_in[1];
    const int*   camids = (const int*)d_in[2];
    const int*   epoch  = (const int*)d_in[3];
    float* out = (float*)d_out;
    char* ws = (char*)d_ws;

    // workspace layout (~42.1 MB; ws proven >= 44 MB in R4-R11)
    unsigned char* xb  = (unsigned char*)ws;                           // 16 MB row-major
    unsigned char* xbt = (unsigned char*)(ws + 16777216);              // 16 MB frag-permuted
    float* sq = (float*)(ws + 33554432);                               // 32 KB
    const size_t NEG_HALVES = (size_t)KL_SYM * NROW * SLOT_P;          // 8 MB
    _Float16* negp = (_Float16*)(ws + 33554432 + 32768);
    _Float16* posf = negp + NEG_HALVES;                                // 128 KB
    float* wsum_p  = (float*)((char*)(posf + (size_t)NROW * SLOT_P));
    float* wpsum_p = wsum_p + MERGE_BLOCKS;

    k_normalize<<<NROW / 4, 256, 0, stream>>>(feats, xb, xbt, sq);
    k_main<<<NPOSB + NTILE, 256, 0, stream>>>(xb, xbt, sq, labels, camids, negp, posf);
    k_merge_sym<<<MERGE_BLOCKS, 256, 0, stream>>>(negp, posf, epoch, out, wsum_p, wpsum_p);
    k_finalize<<<1, 64, 0, stream>>>(wsum_p, wpsum_p, out);
}

// Round 10
// 205.364 us; speedup vs baseline: 2.2714x; 2.2714x over previous
//
#include <hip/hip_runtime.h>
#include <hip/hip_bf16.h>
#include <stdint.h>

// ---- types ----
typedef float   floatx4  __attribute__((ext_vector_type(4)));
typedef float   floatx16 __attribute__((ext_vector_type(16)));
typedef int     intx4    __attribute__((ext_vector_type(4)));
typedef int     intx8    __attribute__((ext_vector_type(8)));
typedef _Float16 halfx8  __attribute__((ext_vector_type(8)));
typedef _Float16 halfx4  __attribute__((ext_vector_type(4)));
typedef _Float16 half2v  __attribute__((ext_vector_type(2)));

#define NROW 8192
#define NDIM 2048        // elements = bytes (fp8)
#define BM 128
#define SLICE 64         // bytes per row per K-slice = K=64 fp8 (one 32x32x64 MFMA)
#define NSLICE 32        // NDIM / SLICE
#define NSTRIP 64                       // NROW/BM
#define NTILE (NSTRIP*(NSTRIP+1)/2)     // 2080 total tiles (= 8*260 exactly)
#define NPOSB 256        // pos blocks prepended to the fused grid
#define DT_LD 136        // Dt row stride in halves (272 B; rows 16B-aligned)
#define KL_SYM 64        // one 5-list per row per other-strip
#define SLOT_P 8         // halves per list slot: 5 values + 3 sentinel pads (16B)
#define MERGE_BLOCKS 256 // k_merge_sym grid
#define BOOST_INV 0.6944444444f   // 1/1.44
// xbt: fragment-permuted copy.  [strip(64)][slice(32)][g(4)][lane(64)] x 32B.
// entry(strip,s,g,l) = xb[strip*128 + 32*g + (l&31)][64*s + 32*(l>>5) .. +32]
// MFMA A-frag (lane=row l&31) AND B-frag (lane=col l&31) have the SAME
// lane->(row,k) mapping -> BOTH operands load as one contiguous 2KB span
// (base + lane*32).  R21: B also reads xbt direct -> K-loop has NO LDS, NO
// barriers (was 32 slice-barrier pairs = the latency-bound plateau R13-R20
// couldn't break; occupancy pinned at 27% regardless of LDS size proved the
// per-block critical path, not residency, was binding).
#define XBT_STRIP 262144   // 32*8192
#define XBT_SLICE 8192

// insert v into descending-sorted a[5] (keeps 5 largest)  [f32 scalar]
__device__ __forceinline__ void ins_desc(float (&a)[5], float v) {
#pragma unroll
    for (int k = 0; k < 5; ++k) { float hi = fmaxf(a[k], v); float lo = fminf(a[k], v); a[k] = hi; v = lo; }
}
// insert v into ascending-sorted a[5] (keeps 5 smallest)  [f32 scalar]
__device__ __forceinline__ void ins_asc(float (&a)[5], float v) {
#pragma unroll
    for (int k = 0; k < 5; ++k) { float lo = fminf(a[k], v); float hi = fmaxf(a[k], v); a[k] = lo; v = hi; }
}

__device__ __forceinline__ int   h2bits(half2v v) { return __builtin_bit_cast(int, v); }
__device__ __forceinline__ half2v bits2h(int v)   { return __builtin_bit_cast(half2v, v); }
// packed insertion: two independent sorted top-5 lists (lo/hi half)
__device__ __forceinline__ void ins_desc2(half2v (&a)[5], half2v v) {
#pragma unroll
    for (int k = 0; k < 5; ++k) {
        half2v hi = __builtin_elementwise_max(a[k], v);
        half2v lo = __builtin_elementwise_min(a[k], v);
        a[k] = hi; v = lo;
    }
}
__device__ __forceinline__ void ins_asc2(half2v (&a)[5], half2v v) {
#pragma unroll
    for (int k = 0; k < 5; ++k) {
        half2v lo = __builtin_elementwise_min(a[k], v);
        half2v hi = __builtin_elementwise_max(a[k], v);
        a[k] = lo; v = hi;
    }
}

__device__ __forceinline__ void load_lds16(const void* g, void* l) {
    // async global->LDS, 16B/lane, dest = wave-uniform base + lane*16
    __builtin_amdgcn_global_load_lds((__attribute__((address_space(1))) void*)(void*)g,
                                     (__attribute__((address_space(3))) void*)l,
                                     16, 0, 0);
}

// ---- kernel 1: L2 normalize rows, write fp8-e4m3 row-major xb + fragment-
// permuted xbt + sq.  One wave per row; xbt stores are 8x32B scatter/instr.
__global__ __launch_bounds__(256) void k_normalize(const float* __restrict__ feats,
                                                   unsigned char* __restrict__ xb,
                                                   unsigned char* __restrict__ xbt,
                                                   float* __restrict__ sq) {
    const int lane = threadIdx.x & 63;
    const int row = (blockIdx.x << 2) + (threadIdx.x >> 6);
    const float* f = feats + (size_t)row * NDIM;
    float4 v[8];
    float ss = 0.f;
#pragma unroll
    for (int i = 0; i < 8; ++i) {
        v[i] = *(const float4*)(f + ((i << 6) + lane) * 4);
        ss += v[i].x * v[i].x + v[i].y * v[i].y + v[i].z * v[i].z + v[i].w * v[i].w;
    }
#pragma unroll
    for (int o = 32; o > 0; o >>= 1) ss += __shfl_xor(ss, o);
    float inv = 1.0f / fmaxf(sqrtf(ss), 1e-12f);
    if (lane == 0) sq[row] = ss * inv * inv;
    unsigned char* xo = xb + (size_t)row * NDIM;
    // xbt dest pieces constant per (row, lane-derived):
    const int strip = row >> 7, rr = row & 127, g = rr >> 5, m32r = rr & 31;
    unsigned char* bt = xbt + (size_t)strip * XBT_STRIP + g * 2048 + m32r * 32
                      + ((lane >> 4) * XBT_SLICE) + (((lane >> 3) & 1) * 1024) + 4 * (lane & 7);
#pragma unroll
    for (int i = 0; i < 8; ++i) {
        int w0 = __builtin_amdgcn_cvt_pk_fp8_f32(v[i].x * inv, v[i].y * inv, 0, false);
        w0     = __builtin_amdgcn_cvt_pk_fp8_f32(v[i].z * inv, v[i].w * inv, w0, true);
        *(int*)(xo + ((i << 6) + lane) * 4) = w0;
        *(int*)(bt + (size_t)4 * i * XBT_SLICE) = w0;   // sG = 4i + (lane>>4)
    }
}

// ---- scan: Dt holds PRE-CLASSIFIED nv (boosted d2; +inf for same-label/diag).
// Insertion-only: load b128 + 4x ins_asc2.
__device__ __forceinline__ void scan_half_row_neg(const _Float16* Dt_,
        int srow, int shalf, float (&neg5)[5]) {
    const int s2 = 2 * (srow & 7);
    const int PINF2 = 0x7C007C00;
    half2v n5[5];
#pragma unroll
    for (int k = 0; k < 5; ++k) n5[k] = bits2h(PINF2);
#pragma unroll
    for (int c8 = 0; c8 < 8; ++c8) {
        const int pc = ((shalf * 8 + c8) + s2) & 15;      // physical 16B chunk
        intx4 v = *(const intx4*)(Dt_ + srow * DT_LD + pc * 8);
#pragma unroll
        for (int e = 0; e < 4; ++e) ins_asc2(n5, bits2h(v[e]));
    }
    // fold hi-halves into lo halves (top5 ⊆ union of half-top5s)
    half2v tn[5];
#pragma unroll
    for (int k = 0; k < 5; ++k)
        tn[k] = bits2h((int)__builtin_amdgcn_alignbit((unsigned)h2bits(n5[k]), (unsigned)h2bits(n5[k]), 16));
#pragma unroll
    for (int k = 0; k < 5; ++k) ins_asc2(n5, tn[k]);
#pragma unroll
    for (int k = 0; k < 5; ++k) neg5[k] = (float)n5[k][0];
}

// merge the two half-row lists (adjacent lanes) and emit one coalesced b128
__device__ __forceinline__ void emit_neg(float (&neg5)[5], int shalf,
        _Float16* negp, int gi, int slot) {
    float tn[5];
#pragma unroll
    for (int k = 0; k < 5; ++k) tn[k] = __shfl_xor(neg5[k], 1);
#pragma unroll
    for (int k = 0; k < 5; ++k) { if (tn[k] < neg5[4]) ins_asc(neg5, tn[k]); }
    if (shalf == 0) {
        const float PINF = __builtin_inff();
        halfx8 hn;
#pragma unroll
        for (int k = 0; k < 5; ++k) hn[k] = (_Float16)neg5[k];
        hn[5] = hn[6] = hn[7] = (_Float16)PINF;
        *(halfx8*)(negp + ((size_t)slot * NROW + gi) * SLOT_P) = hn;
    }
}

// ---- fused kernel 2: blocks [0,256) = positives; [256, 2336) = tiles.
// R21: barrier-free register-dataflow K-loop; both MFMA operands direct from
// xbt (coalesced 2KB spans).  LDS holds only Dt + side arrays.  (256,3): R9's
// (256,4) proved the 128-reg cap spills the 64-reg acc to scratch (922MB
// scratch writes, 3.4x regression).
__global__ __launch_bounds__(256, 3) void k_main(
        const unsigned char* __restrict__ xb, const unsigned char* __restrict__ xbt,
        const float* __restrict__ sq,
        const int* __restrict__ labels, const int* __restrict__ camids,
        _Float16* __restrict__ negp, _Float16* __restrict__ posf) {
    __shared__ __align__(16) char smem[36864];

    const int tid = threadIdx.x;
    const int w = tid >> 6, lane = tid & 63;
    const int m32 = lane & 31;
    const int hi = lane >> 5;
    const float FINF = __builtin_inff();
    const float NINF = -FINF;

    if (blockIdx.x < NPOSB) {
        // ================= positives path (one block per label) =================
        char* stg0 = smem;                                   // 3 x 4096
        _Float16* D2 = (_Float16*)(smem + 12288);            // [64][72] halves
        int* mem = (int*)(smem + 21504);                     // 64 ints
        unsigned short* mlc = (unsigned short*)(smem + 21760);
        float* msq = (float*)(smem + 21888);
        int* cntp = (int*)(smem + 22144);

        const int key = (lane >> 1) & 3;
        const int p0 = ((2 * hi + key) & 3) * 16;
        const int p1 = ((2 * hi + 1 + key) & 3) * 16;

        const int L = blockIdx.x;
        if (tid == 0) *cntp = 0;
        __syncthreads();
        for (int i = tid; i < NROW; i += 256) {
            if (labels[i] == L) {
                int slot = atomicAdd(cntp, 1);
                if (slot < 64) mem[slot] = i;
            }
        }
        __syncthreads();
        const int cnt = min(*cntp, 64);   // P(group>64) ~ 2e-6
        if (tid < 64) {
            if (tid < cnt) {
                int gi = mem[tid];
                mlc[tid] = (unsigned short)((labels[gi] << 4) | camids[gi]);
                msq[tid] = sq[gi];
            } else {
                mem[tid] = 0; mlc[tid] = 0xFFFF; msq[tid] = 0.f;  // sentinel
            }
        }
        __syncthreads();

        const int wm = w >> 1, wn = w & 1;
        const int lr = lane >> 2;
        const int lcb = (((lane & 3) - ((lane >> 3) & 3)) & 3) * 16;
        const int myrow = mem[w * 16 + lr];          // wave w stages rows w*16..+15

        auto pstage = [&](int buf, int koff) {
            load_lds16(xb + (size_t)myrow * NDIM + koff + lcb,
                       stg0 + (buf << 12) + w * 1024);
        };

        floatx16 acc;
#pragma unroll
        for (int r = 0; r < 16; ++r) acc[r] = 0.f;

        pstage(0, 0);                    // depth-2 fill (1 load/wave/slice)
        pstage(1, SLICE);
        for (int s = 0; s < NSLICE; ++s) {
            if (s + 2 < NSLICE) pstage((s + 2) % 3, (s + 2) * SLICE);
            if (s < NSLICE - 2)       asm volatile("s_waitcnt vmcnt(2)" ::: "memory");
            else if (s == NSLICE - 2) asm volatile("s_waitcnt vmcnt(1)" ::: "memory");
            else                      asm volatile("s_waitcnt vmcnt(0)" ::: "memory");
            __builtin_amdgcn_s_barrier();
            asm volatile("" ::: "memory");
            const char* Ab = stg0 + ((s % 3) << 12);
            const char* ap = Ab + (wm * 32 + m32) * SLICE;
            intx4 alo = *(const intx4*)(ap + p0);
            intx4 ahi = *(const intx4*)(ap + p1);
            intx8 af = __builtin_shufflevector(alo, ahi, 0, 1, 2, 3, 4, 5, 6, 7);
            const char* bp = Ab + (wn * 32 + m32) * SLICE;
            intx4 blo = *(const intx4*)(bp + p0);
            intx4 bhi = *(const intx4*)(bp + p1);
            intx8 bf = __builtin_shufflevector(blo, bhi, 0, 1, 2, 3, 4, 5, 6, 7);
            acc = __builtin_amdgcn_mfma_scale_f32_32x32x64_f8f6f4(af, bf, acc, 0, 0, 0, 127, 0, 127);
            asm volatile("" ::: "memory");
            __builtin_amdgcn_s_barrier();
            asm volatile("" ::: "memory");
        }

        // epilogue: masked d2 -> D2[il][jl]; valid pos <=> same label, cross-cam
        {
            const int jl = (w & 1) * 32 + m32;
            const int lcj = (int)mlc[jl];
            const float sj = msq[jl];
            const int wm2 = w >> 1;
#pragma unroll
            for (int r = 0; r < 16; ++r) {
                const int il = wm2 * 32 + (r & 3) + 8 * (r >> 2) + 4 * hi;
                float d2 = fmaxf(msq[il] + sj - 2.0f * acc[r], 1e-12f);
                const int x = (int)mlc[il] ^ lcj;
                bool posv = ((x & 0xFFF0) == 0) & ((x & 15) != 0);
                D2[il * 72 + jl] = posv ? (_Float16)d2 : (_Float16)NINF;
            }
        }
        __syncthreads();

        // per-row top5: 4 threads/row x 16 cols, packed insert + shfl merge
        {
            const int prow = tid >> 2, q = tid & 3;
            const int NINF2 = 0xFC00FC00;
            half2v p5h[5];
#pragma unroll
            for (int k = 0; k < 5; ++k) p5h[k] = bits2h(NINF2);
            const _Float16* dp = D2 + prow * 72 + q * 16;
            intx4 v0 = *(const intx4*)dp;
            intx4 v1 = *(const intx4*)(dp + 8);
#pragma unroll
            for (int e = 0; e < 4; ++e) ins_desc2(p5h, bits2h(v0[e]));
#pragma unroll
            for (int e = 0; e < 4; ++e) ins_desc2(p5h, bits2h(v1[e]));
            half2v tp[5];
#pragma unroll
            for (int k = 0; k < 5; ++k)
                tp[k] = bits2h((int)__builtin_amdgcn_alignbit((unsigned)h2bits(p5h[k]), (unsigned)h2bits(p5h[k]), 16));
#pragma unroll
            for (int k = 0; k < 5; ++k) ins_desc2(p5h, tp[k]);
            float p5[5];
#pragma unroll
            for (int k = 0; k < 5; ++k) p5[k] = (float)p5h[k][0];
#pragma unroll
            for (int o = 1; o <= 2; o <<= 1) {
                float tq[5];
#pragma unroll
                for (int k = 0; k < 5; ++k) tq[k] = __shfl_xor(p5[k], o);
#pragma unroll
                for (int k = 0; k < 5; ++k) { if (tq[k] > p5[4]) ins_desc(p5, tq[k]); }
            }
            if (q == 0 && prow < cnt) {
                halfx8 hp;
#pragma unroll
                for (int k = 0; k < 5; ++k) hp[k] = (_Float16)p5[k];
                hp[5] = hp[6] = hp[7] = (_Float16)NINF;
                *(halfx8*)(posf + (size_t)mem[prow] * SLOT_P) = hp;
            }
        }
        return;
    }

    // ================= tile (negatives) path =================
    _Float16* Dt = (_Float16*)smem;           // [0, 34816)
    float* sqr_s = (float*)(smem + 34816);
    float* sqc_s = sqr_s + BM;
    unsigned short* labcam_a = (unsigned short*)(sqc_s + BM);
    unsigned short* labcam_b = labcam_a + BM;

    const int wm = w >> 1, wn = w & 1;

    // supertile decode; XCD-chunked (2080 = 8*260 exact, bijective)
    int a, b;
    {
        int bx = blockIdx.x - NPOSB;
        int o = (bx & 7) * (NTILE / 8) + (bx >> 3);
        if (o < 1792) {                          // 28 off-diag supertiles x 64
            int st = o >> 6;                     // SA>SB triangle, 8 strips
            int SA = (int)((1.0f + sqrtf(8.0f * (float)st + 1.0f)) * 0.5f);
            while (SA * (SA - 1) / 2 > st) --SA;
            while (SA * (SA + 1) / 2 <= st) ++SA;
            int SB = st - SA * (SA - 1) / 2;
            int inner = o & 63;
            a = SA * 8 + (inner >> 3);
            b = SB * 8 + (inner & 7);
        } else {                                 // 8 diag supertiles x 36
            int idx = o - 1792;
            int st = idx / 36;
            int inner = idx - st * 36;           // triangle incl diagonal
            int ia = (int)((sqrtf(8.0f * (float)inner + 1.0f) - 1.0f) * 0.5f);
            while (ia * (ia + 1) / 2 > inner) --ia;
            while ((ia + 1) * (ia + 2) / 2 <= inner) ++ia;
            int ib = inner - ia * (ia + 1) / 2;
            a = st * 8 + ia;
            b = st * 8 + ib;
        }
    }
    const int r0 = a * BM, c0 = b * BM;

    if (tid < BM) {
        int gi = r0 + tid;
        sqr_s[tid] = sq[gi];
        labcam_a[tid] = (unsigned short)((labels[gi] << 4) | camids[gi]);
    } else {
        int t2 = tid - BM;
        int gj = c0 + t2;
        sqc_s[t2] = sq[gj];
        labcam_b[t2] = (unsigned short)((labels[gj] << 4) | camids[gj]);
    }
    __syncthreads();                 // side arrays visible to all waves

    // Both operands direct from xbt: contiguous per-lane 32B spans
    const unsigned char* aptr0 = xbt + (size_t)a * XBT_STRIP + (2 * wm) * 2048 + lane * 32;
    const unsigned char* aptr1 = aptr0 + 2048;
    const unsigned char* bptr0 = xbt + (size_t)b * XBT_STRIP + (2 * wn) * 2048 + lane * 32;
    const unsigned char* bptr1 = bptr0 + 2048;

    intx4 xa0, xa1, xa2, xa3, xq0, xq1, xq2, xq3;   // even-slice frags (A ti0/1, B tj0/1)
    intx4 ya0, ya1, ya2, ya3, yq0, yq1, yq2, yq3;   // odd-slice frags

    // prologue: depth-2 (2 slices = 16 loads in flight)
    xa0 = *(const intx4*)(aptr0);       xa1 = *(const intx4*)(aptr0 + 16);
    xa2 = *(const intx4*)(aptr1);       xa3 = *(const intx4*)(aptr1 + 16);
    xq0 = *(const intx4*)(bptr0);       xq1 = *(const intx4*)(bptr0 + 16);
    xq2 = *(const intx4*)(bptr1);       xq3 = *(const intx4*)(bptr1 + 16);
    ya0 = *(const intx4*)(aptr0 + XBT_SLICE); ya1 = *(const intx4*)(aptr0 + XBT_SLICE + 16);
    ya2 = *(const intx4*)(aptr1 + XBT_SLICE); ya3 = *(const intx4*)(aptr1 + XBT_SLICE + 16);
    yq0 = *(const intx4*)(bptr0 + XBT_SLICE); yq1 = *(const intx4*)(bptr0 + XBT_SLICE + 16);
    yq2 = *(const intx4*)(bptr1 + XBT_SLICE); yq3 = *(const intx4*)(bptr1 + XBT_SLICE + 16);

    const int srow = tid >> 1;       // scan: 2 threads per row
    const int shalf = tid & 1;

    floatx16 acc[2][2];
#pragma unroll
    for (int ti = 0; ti < 2; ++ti)
#pragma unroll
        for (int tj = 0; tj < 2; ++tj)
#pragma unroll
            for (int r = 0; r < 16; ++r) acc[ti][tj][r] = 0.f;

    for (int s = 0; s < NSLICE; s += 2) {
        // ---- slice s (even): frags in x-set ----
        {
            intx8 af0 = __builtin_shufflevector(xa0, xa1, 0, 1, 2, 3, 4, 5, 6, 7);
            intx8 af1 = __builtin_shufflevector(xa2, xa3, 0, 1, 2, 3, 4, 5, 6, 7);
            intx8 bf0 = __builtin_shufflevector(xq0, xq1, 0, 1, 2, 3, 4, 5, 6, 7);
            intx8 bf1 = __builtin_shufflevector(xq2, xq3, 0, 1, 2, 3, 4, 5, 6, 7);
            __builtin_amdgcn_s_setprio(1);
            acc[0][0] = __builtin_amdgcn_mfma_scale_f32_32x32x64_f8f6f4(af0, bf0, acc[0][0], 0, 0, 0, 127, 0, 127);
            acc[0][1] = __builtin_amdgcn_mfma_scale_f32_32x32x64_f8f6f4(af0, bf1, acc[0][1], 0, 0, 0, 127, 0, 127);
            acc[1][0] = __builtin_amdgcn_mfma_scale_f32_32x32x64_f8f6f4(af1, bf0, acc[1][0], 0, 0, 0, 127, 0, 127);
            acc[1][1] = __builtin_amdgcn_mfma_scale_f32_32x32x64_f8f6f4(af1, bf1, acc[1][1], 0, 0, 0, 127, 0, 127);
            __builtin_amdgcn_s_setprio(0);
        }
        if (s + 2 < NSLICE) {
            const size_t ko = (size_t)(s + 2) * XBT_SLICE;
            xa0 = *(const intx4*)(aptr0 + ko); xa1 = *(const intx4*)(aptr0 + ko + 16);
            xa2 = *(const intx4*)(aptr1 + ko); xa3 = *(const intx4*)(aptr1 + ko + 16);
            xq0 = *(const intx4*)(bptr0 + ko); xq1 = *(const intx4*)(bptr0 + ko + 16);
            xq2 = *(const intx4*)(bptr1 + ko); xq3 = *(const intx4*)(bptr1 + ko + 16);
        }
        // ---- slice s+1 (odd): frags in y-set ----
        {
            intx8 af0 = __builtin_shufflevector(ya0, ya1, 0, 1, 2, 3, 4, 5, 6, 7);
            intx8 af1 = __builtin_shufflevector(ya2, ya3, 0, 1, 2, 3, 4, 5, 6, 7);
            intx8 bf0 = __builtin_shufflevector(yq0, yq1, 0, 1, 2, 3, 4, 5, 6, 7);
            intx8 bf1 = __builtin_shufflevector(yq2, yq3, 0, 1, 2, 3, 4, 5, 6, 7);
            __builtin_amdgcn_s_setprio(1);
            acc[0][0] = __builtin_amdgcn_mfma_scale_f32_32x32x64_f8f6f4(af0, bf0, acc[0][0], 0, 0, 0, 127, 0, 127);
            acc[0][1] = __builtin_amdgcn_mfma_scale_f32_32x32x64_f8f6f4(af0, bf1, acc[0][1], 0, 0, 0, 127, 0, 127);
            acc[1][0] = __builtin_amdgcn_mfma_scale_f32_32x32x64_f8f6f4(af1, bf0, acc[1][0], 0, 0, 0, 127, 0, 127);
            acc[1][1] = __builtin_amdgcn_mfma_scale_f32_32x32x64_f8f6f4(af1, bf1, acc[1][1], 0, 0, 0, 127, 0, 127);
            __builtin_amdgcn_s_setprio(0);
        }
        if (s + 3 < NSLICE) {
            const size_t ko = (size_t)(s + 3) * XBT_SLICE;
            ya0 = *(const intx4*)(aptr0 + ko); ya1 = *(const intx4*)(aptr0 + ko + 16);
            ya2 = *(const intx4*)(aptr1 + ko); ya3 = *(const intx4*)(aptr1 + ko + 16);
            yq0 = *(const intx4*)(bptr0 + ko); yq1 = *(const intx4*)(bptr0 + ko + 16);
            yq2 = *(const intx4*)(bptr1 + ko); yq3 = *(const intx4*)(bptr1 + ko + 16);
        }
    }

    // ---- pass 1: classify once (symmetric), write nv row-major; acc := nv ----
    // 32x32 C layout: col = lane&31, row = (reg&3)+8*(reg>>2)+4*hi
    {
        const int jl0 = wn * 64 + m32, jl1 = jl0 + 32;
        const float sj0 = sqc_s[jl0], sj1 = sqc_s[jl1];
        const int lb0 = (int)labcam_b[jl0], lb1 = (int)labcam_b[jl1];
        const int jc0 = jl0 >> 3, j7_0 = jl0 & 7;
        const int jc1 = jl1 >> 3, j7_1 = jl1 & 7;
#pragma unroll
        for (int ti = 0; ti < 2; ++ti) {
#pragma unroll
            for (int r = 0; r < 16; ++r) {
                const int il = wm * 64 + ti * 32 + (r & 3) + 8 * (r >> 2) + 4 * hi;
                const float si = sqr_s[il];
                const int la = (int)labcam_a[il];
                const int rot = 2 * (il & 7);
                _Float16* drow = Dt + il * DT_LD;

                float d2 = fmaxf(si + sj0 - 2.0f * acc[ti][0][r], 1e-12f);
                int x = la ^ lb0;
                float nv = (x & 15) ? d2 : d2 * BOOST_INV;
                nv = (x & 0xFFF0) ? nv : FINF;
                acc[ti][0][r] = nv;
                drow[(((jc0 + rot) & 15) << 3) + j7_0] = (_Float16)nv;

                d2 = fmaxf(si + sj1 - 2.0f * acc[ti][1][r], 1e-12f);
                x = la ^ lb1;
                nv = (x & 15) ? d2 : d2 * BOOST_INV;
                nv = (x & 0xFFF0) ? nv : FINF;
                acc[ti][1][r] = nv;
                drow[(((jc1 + rot) & 15) << 3) + j7_1] = (_Float16)nv;
            }
        }
    }
    __syncthreads();

    float neg5[5];
    scan_half_row_neg(Dt, srow, shalf, neg5);
    emit_neg(neg5, shalf, negp, r0 + srow, b);

    if (a != b) {
        __syncthreads();             // pass-1 scan reads done before Dt overwrite
        // ---- pass 2: re-layout nv transposed from acc (no recompute) ----
#pragma unroll
        for (int tj = 0; tj < 2; ++tj) {
#pragma unroll
            for (int ti = 0; ti < 2; ++ti) {
                const int jl = wn * 64 + tj * 32 + m32;   // Dt row
                const int cw2 = 2 * (jl & 7);
#pragma unroll
                for (int rq = 0; rq < 4; ++rq) {
                    const int base_row = wm * 64 + ti * 32 + 8 * rq + 4 * hi;
                    halfx4 h;
#pragma unroll
                    for (int e = 0; e < 4; ++e) h[e] = (_Float16)acc[ti][tj][rq * 4 + e];
                    const int pch = (((base_row >> 3) + cw2) & 15);
                    *(halfx4*)(Dt + jl * DT_LD + (pch << 3) + 4 * hi) = h;
                }
            }
        }
        __syncthreads();
        scan_half_row_neg(Dt, srow, shalf, neg5);
        emit_neg(neg5, shalf, negp, c0 + srow, a);
    }
}

// ---- kernel 3: merge 64 fp16 neg-lists/row + final pos list ----
__global__ __launch_bounds__(256) void k_merge_sym(const _Float16* __restrict__ negp,
        const _Float16* __restrict__ posf, const int* __restrict__ epoch_p,
        float* __restrict__ out, float* __restrict__ wsum_p, float* __restrict__ wpsum_p) {
    const int t = threadIdx.x;
    const int rl = t & 31;
    const int sg = t >> 5;
    const int row = blockIdx.x * 32 + rl;
    const float NINF = -__builtin_inff(), PINF = __builtin_inff();
    float n5[5] = {PINF, PINF, PINF, PINF, PINF};
    const size_t rbase = (size_t)row * SLOT_P;
#pragma unroll
    for (int s = 0; s < 8; ++s) {
        const size_t off = (size_t)(sg * 8 + s) * ((size_t)NROW * SLOT_P) + rbase;
        halfx8 nv = *(const halfx8*)(negp + off);
#pragma unroll
        for (int e = 0; e < 8; ++e) { float f = (float)nv[e]; if (f < n5[4]) ins_asc(n5, f); }
    }
    __shared__ __align__(16) _Float16 ln[32][8][8];
    const int sw = (sg + rl) & 7;
    {
        halfx8 hn;
#pragma unroll
        for (int k = 0; k < 5; ++k) hn[k] = (_Float16)n5[k];
        hn[5] = hn[6] = hn[7] = (_Float16)PINF;
        *(halfx8*)&ln[rl][sw][0] = hn;
    }
    __syncthreads();
    if (t < 32) {
        float N5[5] = {PINF, PINF, PINF, PINF, PINF};
#pragma unroll
        for (int g = 0; g < 8; ++g) {
            halfx8 nv = *(const halfx8*)&ln[t][g][0];
#pragma unroll
            for (int e = 0; e < 8; ++e) { float f = (float)nv[e]; if (f < N5[4]) ins_asc(N5, f); }
        }
        const int orow = blockIdx.x * 32 + t;
        halfx8 pv = *(const halfx8*)(posf + (size_t)orow * SLOT_P);
        float s = 0.f; int c = 0;
#pragma unroll
        for (int k = 0; k < 5; ++k) { float f = (float)pv[k]; bool fin = (f > NINF); s += fin ? sqrtf(f) : 0.f; c += fin ? 1 : 0; }
        float d_ap = (c > 0) ? s / (float)c : NINF;
        s = 0.f; c = 0;
#pragma unroll
        for (int k = 0; k < 5; ++k) { bool fin = (N5[k] < PINF); s += fin ? sqrtf(N5[k]) : 0.f; c += fin ? 1 : 0; }
        float d_an = (c > 0) ? s / (float)c : PINF;

        out[1 + orow] = d_ap;
        out[1 + NROW + orow] = d_an;
        float diff = d_ap - d_an;
        float w0 = 1.0f / (1.0f + expf(-2.0f * diff));       // sigmoid(ALPHA*diff)
        float p;
        if (*epoch_p < 10) {
            p = fmaxf(diff, 0.0f) + log1pf(expf(-fabsf(diff)));  // stable softplus
        } else {
            p = fmaxf(diff + 0.3f, 0.0f);                    // relu(diff + MARGIN)
        }
        float wp = w0 * p;
#pragma unroll
        for (int o = 16; o > 0; o >>= 1) { w0 += __shfl_down(w0, o, 32); wp += __shfl_down(wp, o, 32); }
        if (t == 0) { wsum_p[blockIdx.x] = w0; wpsum_p[blockIdx.x] = wp; }
    }
}

// ---- kernel 4: finalize loss scalar (256 partials, one wave) ----
__global__ void k_finalize(const float* __restrict__ wsum_p, const float* __restrict__ wpsum_p,
                           float* __restrict__ out) {
    const int t = threadIdx.x;   // 64 threads
    float sw  = wsum_p[t] + wsum_p[t + 64] + wsum_p[t + 128] + wsum_p[t + 192];
    float swp = wpsum_p[t] + wpsum_p[t + 64] + wpsum_p[t + 128] + wpsum_p[t + 192];
#pragma unroll
    for (int o = 32; o > 0; o >>= 1) { sw += __shfl_down(sw, o); swp += __shfl_down(swp, o); }
    if (t == 0) {
        float M = fmaxf(sw / (float)NROW, 1e-12f);
        out[0] = swp / ((float)NROW * M);
    }
}

extern "C" void kernel_launch(void* const* d_in, const int* in_sizes, int n_in,
                              void* d_out, int out_size, void* d_ws, size_t ws_size,
                              hipStream_t stream) {
    const float* feats  = (const float*)d_in[0];
    const int*   labels = (const int*)d_in[1];
    const int*   camids = (const int*)d_in[2];
    const int*   epoch  = (const int*)d_in[3];
    float* out = (float*)d_out;
    char* ws = (char*)d_ws;

    // workspace layout (~42.1 MB; ws proven >= 44 MB in R4-R11)
    unsigned char* xb  = (unsigned char*)ws;                           // 16 MB row-major
    unsigned char* xbt = (unsigned char*)(ws + 16777216);              // 16 MB frag-permuted
    float* sq = (float*)(ws + 33554432);                               // 32 KB
    const size_t NEG_HALVES = (size_t)KL_SYM * NROW * SLOT_P;          // 8 MB
    _Float16* negp = (_Float16*)(ws + 33554432 + 32768);
    _Float16* posf = negp + NEG_HALVES;                                // 128 KB
    float* wsum_p  = (float*)((char*)(posf + (size_t)NROW * SLOT_P));
    float* wpsum_p = wsum_p + MERGE_BLOCKS;

    k_normalize<<<NROW / 4, 256, 0, stream>>>(feats, xb, xbt, sq);
    k_main<<<NPOSB + NTILE, 256, 0, stream>>>(xb, xbt, sq, labels, camids, negp, posf);
    k_merge_sym<<<MERGE_BLOCKS, 256, 0, stream>>>(negp, posf, epoch, out, wsum_p, wpsum_p);
    k_finalize<<<1, 64, 0, stream>>>(wsum_p, wpsum_p, out);
}